// Round 3
// baseline (44.582 us; speedup 1.0000x reference)
//
#include <hip/hip_runtime.h>

// IntervalTimeEncoder:
//   diff = ts[:,1:] - ts[:,:-1]                       [B, L]
//   idx  = clamp(floor(diff / PER_TIME), 0, 511)       (relu + JAX gather-clamp)
//   out0 = W[idx] + b                                  [B, L, 64] f32
//   out1 = ts[:, :-1]                                  [B, L]     f32
// d_in: [0]=input (int32, UNUSED), [1]=timestamp f32 [B, L+1], [2]=W f32 [512,64], [3]=b f32 [64]
// d_out: out0 (B*L*64 floats) then out1 (B*L floats), concatenated flat.
//
// R3: same as R2 (grid-stride, 16 units/thread in batches of 4 for MLP,
// nontemporal streaming stores) but with clang ext_vector_type float4 --
// __builtin_nontemporal_store rejects HIP_vector_type classes.

#define B_DIM 64
#define L_DIM 8192
#define TIME_DIM 64
#define N_TI 512

#define GRID 2048
#define BLOCK 256
#define NTHREADS (GRID * BLOCK)            // 524288 = 2^19, multiple of 16
#define TOTAL_UNITS (B_DIM * L_DIM * (TIME_DIM / 4))  // 8388608
#define UNITS_PER_THREAD (TOTAL_UNITS / NTHREADS)     // 16
#define ROW_STRIDE (NTHREADS / 16)         // rows advance per iteration: 32768

typedef float f32x4 __attribute__((ext_vector_type(4)));

__global__ __launch_bounds__(256) void IntervalTimeEncoder_77653008712021_kernel(
    const float* __restrict__ ts,     // [B, L+1]
    const float* __restrict__ W,      // [512, 64]
    const float* __restrict__ bias,   // [64]
    float* __restrict__ emb,          // [B, L, 64]
    float* __restrict__ ts_out)       // [B, L]
{
    const int tid  = blockIdx.x * BLOCK + threadIdx.x;  // 0 .. NTHREADS-1
    const int d4   = tid & 15;                          // loop-invariant
    const int row0 = tid >> 4;                          // 0 .. 32767

    const f32x4 bb = reinterpret_cast<const f32x4*>(bias)[d4];
    const f32x4* __restrict__ W4 = reinterpret_cast<const f32x4*>(W);
    f32x4* __restrict__ emb4 = reinterpret_cast<f32x4*>(emb);

    #pragma unroll
    for (int k = 0; k < UNITS_PER_THREAD; k += 4) {
        int   rows[4];
        float t0[4], t1[4];

        // Phase 1: issue all ts loads (independent -> overlap latency)
        #pragma unroll
        for (int j = 0; j < 4; ++j) {
            const int row  = row0 + (k + j) * ROW_STRIDE;
            const int b    = row >> 13;          // / L_DIM
            const int l    = row & (L_DIM - 1);
            const int base = b * (L_DIM + 1) + l;
            rows[j] = row;
            t0[j] = ts[base];
            t1[j] = ts[base + 1];
        }

        // Phase 2: compute indices, issue all W gathers
        f32x4 w[4];
        #pragma unroll
        for (int j = 0; j < 4; ++j) {
            const float diff = t1[j] - t0[j];
            // bit-match jnp: true f32 divide (1/PER_TIME not representable), floor,
            // relu, JAX gather-clamp
            int idx = (int)floorf(diff / 1953.125f);
            idx = idx < 0 ? 0 : idx;
            idx = idx > (N_TI - 1) ? (N_TI - 1) : idx;
            w[j] = W4[idx * (TIME_DIM / 4) + d4];
        }

        // Phase 3: bias-add + streaming stores
        #pragma unroll
        for (int j = 0; j < 4; ++j) {
            f32x4 o = w[j] + bb;
            __builtin_nontemporal_store(o, &emb4[(size_t)rows[j] * (TIME_DIM / 4) + d4]);
            if (d4 == 0) {
                __builtin_nontemporal_store(t0[j], &ts_out[rows[j]]);
            }
        }
    }
}

extern "C" void kernel_launch(void* const* d_in, const int* in_sizes, int n_in,
                              void* d_out, int out_size, void* d_ws, size_t ws_size,
                              hipStream_t stream) {
    (void)in_sizes; (void)n_in; (void)d_ws; (void)ws_size; (void)out_size;
    // d_in[0] = input (int32) — unused by the reference outputs
    const float* ts   = (const float*)d_in[1];
    const float* W    = (const float*)d_in[2];
    const float* bias = (const float*)d_in[3];

    float* emb    = (float*)d_out;                                     // [B, L, 64]
    float* ts_out = (float*)d_out + (size_t)B_DIM * L_DIM * TIME_DIM;  // [B, L]

    IntervalTimeEncoder_77653008712021_kernel<<<GRID, BLOCK, 0, stream>>>(
        ts, W, bias, emb, ts_out);
}

// Round 4
// 29.134 us; speedup vs baseline: 1.5302x; 1.5302x over previous
//
#include <hip/hip_runtime.h>

// IntervalTimeEncoder:
//   diff = ts[:,1:] - ts[:,:-1]                       [B, L]
//   idx  = clamp(floor(diff / PER_TIME), 0, 511)       (relu + JAX gather-clamp)
//   out0 = W[idx] + b                                  [B, L, 64] f32
//   out1 = ts[:, :-1]                                  [B, L]     f32
// d_in: [0]=input (int32, UNUSED), [1]=timestamp f32 [B, L+1], [2]=W f32 [512,64], [3]=b f32 [64]
// d_out: out0 (B*L*64 floats) then out1 (B*L floats), concatenated flat.
//
// R4: R3 with nontemporal stores REMOVED (single-variable isolation).
// R1 (32768 blocks, 1 unit/thread, plain stores)         = 28.9 us
// R3 (2048 blocks, 16 units/thread batched, NT stores)   = 44.6 us
// Theory: NT bypasses L2 write-combining and wrecked the store stream
// (97% of traffic). Batching/grid-stride itself should be neutral-to-positive
// (kills 32768-workgroup dispatch overhead; per-wave stores still 1KiB
// contiguous per instruction).

#define B_DIM 64
#define L_DIM 8192
#define TIME_DIM 64
#define N_TI 512

#define GRID 2048
#define BLOCK 256
#define NTHREADS (GRID * BLOCK)            // 524288 = 2^19, multiple of 16
#define TOTAL_UNITS (B_DIM * L_DIM * (TIME_DIM / 4))  // 8388608
#define UNITS_PER_THREAD (TOTAL_UNITS / NTHREADS)     // 16
#define ROW_STRIDE (NTHREADS / 16)         // rows advance per iteration: 32768

typedef float f32x4 __attribute__((ext_vector_type(4)));

__global__ __launch_bounds__(256) void IntervalTimeEncoder_77653008712021_kernel(
    const float* __restrict__ ts,     // [B, L+1]
    const float* __restrict__ W,      // [512, 64]
    const float* __restrict__ bias,   // [64]
    float* __restrict__ emb,          // [B, L, 64]
    float* __restrict__ ts_out)       // [B, L]
{
    const int tid  = blockIdx.x * BLOCK + threadIdx.x;  // 0 .. NTHREADS-1
    const int d4   = tid & 15;                          // loop-invariant
    const int row0 = tid >> 4;                          // 0 .. 32767

    const f32x4 bb = reinterpret_cast<const f32x4*>(bias)[d4];
    const f32x4* __restrict__ W4 = reinterpret_cast<const f32x4*>(W);
    f32x4* __restrict__ emb4 = reinterpret_cast<f32x4*>(emb);

    #pragma unroll
    for (int k = 0; k < UNITS_PER_THREAD; k += 4) {
        int   rows[4];
        float t0[4], t1[4];

        // Phase 1: issue all ts loads (independent -> overlap latency)
        #pragma unroll
        for (int j = 0; j < 4; ++j) {
            const int row  = row0 + (k + j) * ROW_STRIDE;
            const int b    = row >> 13;          // / L_DIM
            const int l    = row & (L_DIM - 1);
            const int base = b * (L_DIM + 1) + l;
            rows[j] = row;
            t0[j] = ts[base];
            t1[j] = ts[base + 1];
        }

        // Phase 2: compute indices, issue all W gathers
        f32x4 w[4];
        #pragma unroll
        for (int j = 0; j < 4; ++j) {
            const float diff = t1[j] - t0[j];
            // bit-match jnp: true f32 divide (1/PER_TIME not representable), floor,
            // relu, JAX gather-clamp
            int idx = (int)floorf(diff / 1953.125f);
            idx = idx < 0 ? 0 : idx;
            idx = idx > (N_TI - 1) ? (N_TI - 1) : idx;
            w[j] = W4[idx * (TIME_DIM / 4) + d4];
        }

        // Phase 3: bias-add + plain coalesced stores (NT removed)
        #pragma unroll
        for (int j = 0; j < 4; ++j) {
            emb4[(size_t)rows[j] * (TIME_DIM / 4) + d4] = w[j] + bb;
            if (d4 == 0) {
                ts_out[rows[j]] = t0[j];
            }
        }
    }
}

extern "C" void kernel_launch(void* const* d_in, const int* in_sizes, int n_in,
                              void* d_out, int out_size, void* d_ws, size_t ws_size,
                              hipStream_t stream) {
    (void)in_sizes; (void)n_in; (void)d_ws; (void)ws_size; (void)out_size;
    // d_in[0] = input (int32) — unused by the reference outputs
    const float* ts   = (const float*)d_in[1];
    const float* W    = (const float*)d_in[2];
    const float* bias = (const float*)d_in[3];

    float* emb    = (float*)d_out;                                     // [B, L, 64]
    float* ts_out = (float*)d_out + (size_t)B_DIM * L_DIM * TIME_DIM;  // [B, L]

    IntervalTimeEncoder_77653008712021_kernel<<<GRID, BLOCK, 0, stream>>>(
        ts, W, bias, emb, ts_out);
}